// Round 9
// baseline (483.348 us; speedup 1.0000x reference)
//
#include <hip/hip_runtime.h>
#include <hip/hip_cooperative_groups.h>

namespace cg = cooperative_groups;

#define C_CLS 50
#define B_TR 8
#define T_FULL 600
#define T_USE 500
#define N_NEU 30000
#define NGRP 118          // ceil(30000/256) groups of 256 neurons
#define NGRP_PAD 120      // padded so bitset rows end in zero words
#define WPC 480           // u64 words per class bitset row = NGRP_PAD*4
#define NQ 30             // quads per row (NGRP_PAD/4)
#define TPB 4             // t-rows per stream block-unit
#define NBT (B_TR * T_USE / TPB)   // 1000 stream units
#define GRID 512
#define NBINS 16
#define EPS 1e-7

__device__ __constant__ int d_bins[NBINS] = {1,1,2,3,4,6,9,13,18,26,38,55,78,113,162,234};

// verdict bits: 1=f32 pattern, 2=packed-bytes, 4=odd-word-nonzero, 8=f64 pattern
__device__ __forceinline__ int mode_from_verdict(int v) {
    if (v & 1) return 2;   // float32
    if (v & 8) return 4;   // float64
    if (v & 2) return 1;   // uint8
    if (v & 4) return 0;   // int32
    return 3;              // int64
}

__device__ __forceinline__ bool load_sel(const void* mask, int mode, long long e) {
    switch (mode) {
        case 0:  return ((const int*)mask)[e] != 0;
        case 1:  return ((const unsigned char*)mask)[e] != 0;
        case 2:  return ((const float*)mask)[e] != 0.0f;
        case 3:  return ((const long long*)mask)[e] != 0LL;
        default: return ((const double*)mask)[e] != 0.0;
    }
}

// ---------------------------------------------------------------------------
// Single fused cooperative kernel. 512 blocks x 256 threads, all co-resident
// (LDS 17KB, launch_bounds(256,2)). Phase boundaries are grid.sync()s
// (~3us) instead of kernel-launch boundaries (~20us each).
// ---------------------------------------------------------------------------
__global__ void __launch_bounds__(256, 2)
fused_kernel(const float* __restrict__ spikes,
             const float* __restrict__ exp_fanos,
             const int* __restrict__ trials,
             const void* __restrict__ mask,
             float* __restrict__ out,
             int* __restrict__ verdict,
             int* __restrict__ ncls,
             int* __restrict__ cls_of_trial,
             unsigned long long* __restrict__ bits,
             float* __restrict__ selected,
             float* __restrict__ fanos) {
    cg::grid_group grid = cg::this_grid();
    __shared__ unsigned long long sbits[TPB][WPC]; // 15,360 B
    __shared__ int wsum2[C_CLS][4][2];             // 1,600 B
    __shared__ int sfl;

    const int bid = blockIdx.x;
    const int tid = threadIdx.x;
    const int lane = tid & 63;
    const int wid = tid >> 6;

    // ================= P0: detect mask encoding + invert sample_trials =====
    {
        if (tid == 0) sfl = 0;
        __syncthreads();
        const unsigned int* w = (const unsigned int*)mask;
        const int nwords = C_CLS * N_NEU / 4; // 375000 (smallest possible buffer)
        int f = 0;
        for (int i = bid * 256 + tid; i < nwords; i += GRID * 256) {
            unsigned int v = w[i];
            if (v == 0u) continue;
            if (v == 0x3F800000u) f |= 1;
            else if (v == 0x3FF00000u && (i & 1)) f |= 8;
            else {
                unsigned int b0 = v & 0xFFu, b1 = (v >> 8) & 0xFFu,
                             b2 = (v >> 16) & 0xFFu, b3 = (v >> 24) & 0xFFu;
                bool byteOK = (b0 <= 1u) && (b1 <= 1u) && (b2 <= 1u) && (b3 <= 1u);
                if (byteOK && v != 1u) f |= 2;
            }
            if (i & 1) f |= 4;
        }
        for (int off = 32; off > 0; off >>= 1) f |= __shfl_xor(f, off);
        if (lane == 0 && f) atomicOr(&sfl, f);
        __syncthreads();
        if (tid == 0) verdict[bid] = sfl;

        if (bid == 0 && tid < 64) { // ballot-deterministic trial inversion
            int b = (lane < C_CLS) ? trials[lane] : -1;
            for (int bb = 0; bb < B_TR; ++bb) {
                unsigned long long m = __ballot(b == bb);
                if (b == bb) {
                    int pos = __popcll(m & ((1ull << lane) - 1ull));
                    cls_of_trial[bb * 64 + pos] = lane;
                }
                if (lane == 0) ncls[bb] = __popcll(m);
            }
        }
    }
    __threadfence();
    grid.sync();

    // ================= P1: reduce mode, build class bitsets =================
    {
        if (tid == 0) sfl = 0;
        __syncthreads();
        int v = verdict[tid] | verdict[tid + 256];
        for (int off = 32; off > 0; off >>= 1) v |= __shfl_xor(v, off);
        if (lane == 0 && v) atomicOr(&sfl, v);
        __syncthreads();
        int mode = mode_from_verdict(sfl);
        // task = (class, group); wave wid builds interleaved word (g, k=wid):
        // bit l = mask[c][g*256 + l*4 + wid]  ->  bits[c*WPC + g*4 + wid]
        for (int task = bid; task < C_CLS * NGRP_PAD; task += GRID) {
            int c = task / NGRP_PAD;
            int g = task - c * NGRP_PAD;
            int n = g * 256 + lane * 4 + wid;
            bool sel = (n < N_NEU) && load_sel(mask, mode, (long long)c * N_NEU + n);
            unsigned long long w = __ballot(sel);
            if (lane == 0) bits[(long long)c * WPC + g * 4 + wid] = w;
        }
    }
    __threadfence();
    grid.sync();

    // ================= P2: stream spikes -> selected ========================
    for (int bt = bid; bt < NBT; bt += GRID) {
        int b = bt / (T_USE / TPB);
        int tq = bt - b * (T_USE / TPB);
        int t0 = tq * TPB;
        int nc = ncls[b];
        if (nc == 0) continue;
        const float4* __restrict__ row4 =
            (const float4*)(spikes + ((long long)(b * T_FULL + t0 + wid)) * N_NEU);

        // phase 1: wave wid ballots its row into sbits[wid]
        for (int q = 0; q < NQ; ++q) {
            float4 v[4];
#pragma unroll
            for (int u = 0; u < 4; ++u) {
                int ia = (q * 4 + u) * 64 + lane;
                if (ia > N_NEU / 4 - 1) ia = N_NEU / 4 - 1; // dups masked by zero bits
                v[u] = row4[ia];
            }
#pragma unroll
            for (int u = 0; u < 4; ++u) {
                unsigned long long b0 = __ballot(v[u].x != 0.0f);
                unsigned long long b1 = __ballot(v[u].y != 0.0f);
                unsigned long long b2 = __ballot(v[u].z != 0.0f);
                unsigned long long b3 = __ballot(v[u].w != 0.0f);
                if (lane == 0) {
                    int o = (q * 4 + u) * 4;
                    sbits[wid][o + 0] = b0; sbits[wid][o + 1] = b1;
                    sbits[wid][o + 2] = b2; sbits[wid][o + 3] = b3;
                }
            }
        }
        __syncthreads();

        // phase 2: coalesced bitset read, 4-row popcount
        int i0 = tid;
        int i1 = tid + 256;
        bool has1 = (i1 < WPC);
        unsigned long long s00 = sbits[0][i0], s10 = sbits[1][i0],
                           s20 = sbits[2][i0], s30 = sbits[3][i0];
        unsigned long long s01 = 0, s11 = 0, s21 = 0, s31 = 0;
        if (has1) { s01 = sbits[0][i1]; s11 = sbits[1][i1];
                    s21 = sbits[2][i1]; s31 = sbits[3][i1]; }
        for (int kc = 0; kc < nc; ++kc) {
            int c = cls_of_trial[b * 64 + kc];
            const unsigned long long* __restrict__ bp = bits + (long long)c * WPC;
            unsigned long long w0 = bp[i0];
            unsigned long long w1 = has1 ? bp[i1] : 0ull;
            int p0 = __popcll(s00 & w0) + __popcll(s01 & w1);
            int p1 = __popcll(s10 & w0) + __popcll(s11 & w1);
            int p2 = __popcll(s20 & w0) + __popcll(s21 & w1);
            int p3 = __popcll(s30 & w0) + __popcll(s31 & w1);
            int pa = p0 | (p1 << 16);  // per-lane <=128, wave sum <=8192: no carry
            int pb = p2 | (p3 << 16);
            for (int off = 32; off > 0; off >>= 1) {
                pa += __shfl_down(pa, off);
                pb += __shfl_down(pb, off);
            }
            if (lane == 0) { wsum2[kc][wid][0] = pa; wsum2[kc][wid][1] = pb; }
        }
        __syncthreads();
        if (tid < nc * 4) {
            int kc = tid >> 2, r = tid & 3;
            int c = cls_of_trial[b * 64 + kc];
            int s = 0;
#pragma unroll
            for (int w = 0; w < 4; ++w) {
                int v = wsum2[kc][w][r >> 1];
                s += (r & 1) ? (v >> 16) : (v & 0xFFFF);
            }
            selected[c * T_USE + t0 + r] = (float)s;
        }
    }
    __threadfence();
    grid.sync();

    // ================= P3: per-bin fano (blocks 0..15, wave 0 only) =========
    if (bid < NBINS && tid < 64) {
        int b = d_bins[bid];
        int nb = T_USE / b;
        int lim = nb * b;
        float fano = 0.f;
        if (lane < C_CLS) {
            const float4* __restrict__ row4 = (const float4*)(selected + lane * T_USE);
            double s1 = 0.0, s2 = 0.0;
            float cs = 0.f;
            int r = b;
            for (int i4 = 0; i4 < T_USE / 4; ++i4) {
                float4 v = row4[i4];
                float comp0 = v.x, comp1 = v.y, comp2 = v.z, comp3 = v.w;
#pragma unroll
                for (int u = 0; u < 4; ++u) {
                    float cv = (u == 0) ? comp0 : (u == 1) ? comp1 : (u == 2) ? comp2 : comp3;
                    int idx = i4 * 4 + u;
                    if (idx < lim) {
                        cs += cv;
                        if (--r == 0) { s1 += cs; s2 += (double)cs * cs; cs = 0.f; r = b; }
                    }
                }
            }
            double mean = s1 / nb;
            double var = s2 / nb - mean * mean;
            if (var < 0.0) var = 0.0;
            double m = mean > EPS ? mean : EPS;
            fano = (float)(var / m);
        }
        for (int off = 32; off > 0; off >>= 1) fano += __shfl_down(fano, off);
        if (lane == 0) fanos[bid] = fano / (float)C_CLS;
    }
    __threadfence();
    grid.sync();

    // ================= P4: MSE loss =========================================
    if (bid == 0 && tid < 64) {
        float sq = 0.f;
        if (lane < NBINS) {
            float d = exp_fanos[lane] - fanos[lane];
            sq = d * d;
        }
        for (int off = 32; off > 0; off >>= 1) sq += __shfl_down(sq, off);
        if (lane == 0) out[0] = 10.0f * sq / (float)NBINS;
    }
}

extern "C" void kernel_launch(void* const* d_in, const int* in_sizes, int n_in,
                              void* d_out, int out_size, void* d_ws, size_t ws_size,
                              hipStream_t stream) {
    const float* spikes    = (const float*)d_in[0];
    const float* exp_fanos = (const float*)d_in[1];
    const int*   trials    = (const int*)d_in[2];
    const void*  mask      = d_in[3];
    float* out = (float*)d_out;

    char* ws = (char*)d_ws;
    int*   verdict = (int*)(ws + 0);        // 512 ints (all stored each launch)
    int*   ncls    = (int*)(ws + 2048);
    int*   clsofb  = (int*)(ws + 2304);
    float* fanos   = (float*)(ws + 4608);
    unsigned long long* bits = (unsigned long long*)(ws + 8192);   // 192,000 B
    float* selected = (float*)(ws + 204800);                       // 100,000 B

    void* args[] = {
        (void*)&spikes, (void*)&exp_fanos, (void*)&trials, (void*)&mask,
        (void*)&out, (void*)&verdict, (void*)&ncls, (void*)&clsofb,
        (void*)&bits, (void*)&selected, (void*)&fanos
    };
    hipLaunchCooperativeKernel((void*)fused_kernel, dim3(GRID), dim3(256),
                               args, 0, stream);
}

// Round 10
// 183.215 us; speedup vs baseline: 2.6382x; 2.6382x over previous
//
#include <hip/hip_runtime.h>

#define C_CLS 50
#define B_TR 8
#define T_FULL 600
#define T_USE 500
#define N_NEU 30000
#define NF4 7500          // float4 per spike row
#define NGRP_PAD 128      // groups of 256 floats (padded; groups>=118 all-zero bits)
#define WPC 512           // u64 words per class bitset row = NGRP_PAD*4
#define NQHALF 16         // quads per half-row (quad = 4 groups = 16 float4/lane)
#define TPB 2             // t-rows per stream block
#define NBT (B_TR * T_USE / TPB)   // 2000 blocks
#define NBINS 16
#define EPS 1e-7
#define LDS_STRIDE 501    // floats; odd -> conflict-free lane-per-class reads

__device__ __constant__ int d_bins[NBINS] = {1,1,2,3,4,6,9,13,18,26,38,55,78,113,162,234};

// ws layout (bytes):
//   verdict      @ 0      int[256] (every launch: plain stores, no init needed)
//   ncls         @ 1024   int[8]
//   cls_of_trial @ 1280   int[8*64]
//   bits         @ 8192   u64[50*512] (204,800 B)
//   selected     @ 212992 float[50*500] (100,000 B)

// verdict bits: 1=f32 pattern, 2=packed-bytes, 4=odd-word-nonzero, 8=f64 pattern
__device__ __forceinline__ int mode_from_verdict(int v) {
    if (v & 1) return 2;   // float32
    if (v & 8) return 4;   // float64
    if (v & 2) return 1;   // uint8
    if (v & 4) return 0;   // int32
    return 3;              // int64
}

__device__ __forceinline__ bool load_sel(const void* mask, int mode, long long e) {
    switch (mode) {
        case 0:  return ((const int*)mask)[e] != 0;
        case 1:  return ((const unsigned char*)mask)[e] != 0;
        case 2:  return ((const float*)mask)[e] != 0.0f;
        case 3:  return ((const long long*)mask)[e] != 0LL;
        default: return ((const double*)mask)[e] != 0.0;
    }
}

// ---------------------------------------------------------------------------
// detect: 256 blocks scan disjoint word partitions, store packed verdicts
// (plain stores -> no pre-zero, no global atomics). Block 0 wave 0 also
// inverts sample_trials into per-trial class lists (ballot-deterministic).
// ---------------------------------------------------------------------------
__global__ void __launch_bounds__(256)
detect_kernel(const unsigned int* __restrict__ w, const int* __restrict__ trials,
              int* verdict, int* ncls, int* cls_of_trial) {
    __shared__ int sfl;
    if (threadIdx.x == 0) sfl = 0;
    __syncthreads();
    const int nwords = C_CLS * N_NEU / 4; // 375000 (smallest possible buffer)
    int per = (nwords + gridDim.x - 1) / gridDim.x;
    int beg = blockIdx.x * per;
    int end = beg + per; if (end > nwords) end = nwords;
    int f = 0;
    for (int i = beg + threadIdx.x; i < end; i += blockDim.x) {
        unsigned int v = w[i];
        if (v == 0u) continue;
        if (v == 0x3F800000u) f |= 1;
        else if (v == 0x3FF00000u && (i & 1)) f |= 8;
        else {
            unsigned int b0 = v & 0xFFu, b1 = (v >> 8) & 0xFFu,
                         b2 = (v >> 16) & 0xFFu, b3 = (v >> 24) & 0xFFu;
            bool byteOK = (b0 <= 1u) && (b1 <= 1u) && (b2 <= 1u) && (b3 <= 1u);
            if (byteOK && v != 1u) f |= 2;
        }
        if (i & 1) f |= 4;
    }
    if (f) atomicOr(&sfl, f);
    __syncthreads();
    if (threadIdx.x == 0) verdict[blockIdx.x] = sfl;

    if (blockIdx.x == 0 && threadIdx.x < 64) {
        int lane = threadIdx.x;
        int b = (lane < C_CLS) ? trials[lane] : -1;
        for (int bb = 0; bb < B_TR; ++bb) {
            unsigned long long m = __ballot(b == bb);
            if (b == bb) {
                int pos = __popcll(m & ((1ull << lane) - 1ull));
                cls_of_trial[bb * 64 + pos] = lane;
            }
            if (lane == 0) ncls[bb] = __popcll(m);
        }
    }
}

// ---------------------------------------------------------------------------
// build_bits: class bitsets in INTERLEAVED order matching the float4 ballot:
// word (g,k) bit l = mask[c][g*256 + l*4 + k] at bits[c*WPC + g*4 + k].
// Groups 118..127 give all-zero words, auto-masking clamped stream loads.
// ---------------------------------------------------------------------------
__global__ void build_bits_kernel(const void* mask, const int* __restrict__ verdict,
                                  unsigned long long* bits) {
    int c = blockIdx.x;
    int lane = threadIdx.x; // 64 = 1 wave
    int v = verdict[lane] | verdict[lane + 64] | verdict[lane + 128] | verdict[lane + 192];
    for (int off = 32; off > 0; off >>= 1) v |= __shfl_xor(v, off);
    int mode = mode_from_verdict(v);
    for (int g = blockIdx.y; g < NGRP_PAD; g += gridDim.y) {
        int base = g * 256 + lane * 4;
        long long e = (long long)c * N_NEU + base;
        bool s0 = (base + 0 < N_NEU) && load_sel(mask, mode, e + 0);
        bool s1 = (base + 1 < N_NEU) && load_sel(mask, mode, e + 1);
        bool s2 = (base + 2 < N_NEU) && load_sel(mask, mode, e + 2);
        bool s3 = (base + 3 < N_NEU) && load_sel(mask, mode, e + 3);
        unsigned long long w0 = __ballot(s0);
        unsigned long long w1 = __ballot(s1);
        unsigned long long w2 = __ballot(s2);
        unsigned long long w3 = __ballot(s3);
        if (lane == 0) {
            long long o = (long long)c * WPC + g * 4;
            bits[o + 0] = w0; bits[o + 1] = w1;
            bits[o + 2] = w2; bits[o + 3] = w3;
        }
    }
}

__device__ __forceinline__ void loadq(float4* v, const float4* __restrict__ row4,
                                      int qq, int lane) {
#pragma unroll
    for (int u = 0; u < 4; ++u) {
        int ia = (qq * 4 + u) * 64 + lane;
        if (ia > NF4 - 1) ia = NF4 - 1; // clamped dups: masked by zero bitset words
        v[u] = row4[ia];
    }
}

__device__ __forceinline__ void consumeq(const float4* v, unsigned long long* sb,
                                         int qq, int lane) {
#pragma unroll
    for (int u = 0; u < 4; ++u) {
        unsigned long long b0 = __ballot(v[u].x != 0.0f);
        unsigned long long b1 = __ballot(v[u].y != 0.0f);
        unsigned long long b2 = __ballot(v[u].z != 0.0f);
        unsigned long long b3 = __ballot(v[u].w != 0.0f);
        if (lane == 0) {
            int o = (qq * 4 + u) * 4;
            sb[o + 0] = b0; sb[o + 1] = b1;
            sb[o + 2] = b2; sb[o + 3] = b3;
        }
    }
}

// ---------------------------------------------------------------------------
// stream: 2000 blocks (one per trial,t-pair) x 256 thr, ~7.8 blocks/CU.
// Wave w ballots half (w&1) of row t0+(w>>1). Depth-2 software pipeline:
// next A/B quad-batches (8 float4 loads) issue BEFORE consuming current ->
// 8-12KB per wave continuously in flight. Phase 2: coalesced per-class
// bitset read, both rows popcounted packed 2x16-bit, wave shuffle-reduce.
// One writer per (c,t) -> deterministic, no atomics, no pre-zero.
// ---------------------------------------------------------------------------
__global__ void __launch_bounds__(256, 4)
stream_kernel(const float* __restrict__ spikes,
              const int* __restrict__ ncls,
              const int* __restrict__ cls_of_trial,
              const unsigned long long* __restrict__ bits,
              float* __restrict__ selected) {
    __shared__ unsigned long long sbits[TPB][WPC]; // 8,192 B
    __shared__ int wsum[C_CLS][4];                 // 800 B
    int bt = blockIdx.x;                 // 0..1999
    int b = bt / (T_USE / TPB);          // /250
    int tq = bt - b * (T_USE / TPB);
    int t0 = tq * TPB;
    int nc = ncls[b];
    if (nc == 0) return;
    int lane = threadIdx.x & 63;
    int wid = threadIdx.x >> 6;
    int r = wid >> 1;                    // row within pair
    int h = wid & 1;                     // half of row
    const float4* __restrict__ row4 =
        (const float4*)(spikes + ((long long)(b * T_FULL + t0 + r)) * N_NEU);

    // ---- phase 1: software-pipelined ballot of this wave's half-row
    int qb = h * NQHALF;
    float4 A[4], B[4], NA[4], NB[4];
    loadq(A, row4, qb + 0, lane);
    loadq(B, row4, qb + 1, lane);
    for (int q = 0; q < NQHALF; q += 2) {
        bool more = (q + 2 < NQHALF);
        if (more) {
            loadq(NA, row4, qb + q + 2, lane);
            loadq(NB, row4, qb + q + 3, lane);
        }
        consumeq(A, sbits[r], qb + q, lane);
        consumeq(B, sbits[r], qb + q + 1, lane);
        if (more) {
#pragma unroll
            for (int u = 0; u < 4; ++u) { A[u] = NA[u]; B[u] = NB[u]; }
        }
    }
    __syncthreads();

    // ---- phase 2: coalesced bitset read, 2-row packed popcount
    int i0 = threadIdx.x;
    int i1 = threadIdx.x + 256;          // < 512 always
    unsigned long long s00 = sbits[0][i0], s01 = sbits[0][i1];
    unsigned long long s10 = sbits[1][i0], s11 = sbits[1][i1];
    for (int kc = 0; kc < nc; ++kc) {
        int c = cls_of_trial[b * 64 + kc];
        const unsigned long long* __restrict__ bp = bits + (long long)c * WPC;
        unsigned long long w0 = bp[i0];
        unsigned long long w1 = bp[i1];
        int p0 = __popcll(s00 & w0) + __popcll(s01 & w1);
        int p1 = __popcll(s10 & w0) + __popcll(s11 & w1);
        int pa = p0 | (p1 << 16);        // per-lane <=128, wave sum <=8192: no carry
        for (int off = 32; off > 0; off >>= 1) pa += __shfl_down(pa, off);
        if (lane == 0) wsum[kc][wid] = pa;
    }
    __syncthreads();
    if (threadIdx.x < nc * 2) {
        int kc = threadIdx.x >> 1, rr = threadIdx.x & 1;
        int c = cls_of_trial[b * 64 + kc];
        int s = 0;
#pragma unroll
        for (int w = 0; w < 4; ++w) {
            int v = wsum[kc][w];
            s += rr ? (v >> 16) : (v & 0xFFFF);
        }
        selected[c * T_USE + t0 + rr] = (float)s;
    }
}

// ---------------------------------------------------------------------------
// fano_loss: one block, 16 waves (wave = bin). Stage `selected` into LDS
// (coalesced float4, stride-501 -> conflict-free lane-per-class reads);
// lane c accumulates bin sums in double (exact); wave 0 does the MSE.
// ---------------------------------------------------------------------------
__global__ void __launch_bounds__(1024)
fano_loss_kernel(const float* __restrict__ selected,
                 const float* __restrict__ exp_fanos,
                 float* __restrict__ out) {
    __shared__ float lds[C_CLS * LDS_STRIDE]; // 100,200 B
    __shared__ float sf[NBINS];
    const float4* __restrict__ sel4 = (const float4*)selected;
    for (int i = threadIdx.x; i < C_CLS * T_USE / 4; i += 1024) {
        float4 v = sel4[i];
        int r = i / (T_USE / 4);
        int p = (i - r * (T_USE / 4)) * 4;
        float* dst = &lds[r * LDS_STRIDE + p];
        dst[0] = v.x; dst[1] = v.y; dst[2] = v.z; dst[3] = v.w;
    }
    __syncthreads();
    int wid = threadIdx.x >> 6;
    int lane = threadIdx.x & 63;
    int b = d_bins[wid];
    int nb = T_USE / b;
    float fano = 0.f;
    if (lane < C_CLS) {
        const float* row = &lds[lane * LDS_STRIDE];
        double s1 = 0.0, s2 = 0.0;
        for (int i = 0; i < nb; ++i) {
            float cs = 0.f;
            int base = i * b;
            for (int j = 0; j < b; ++j) cs += row[base + j];
            s1 += cs;
            s2 += (double)cs * (double)cs;
        }
        double mean = s1 / nb;
        double var = s2 / nb - mean * mean;
        if (var < 0.0) var = 0.0;
        double m = mean > EPS ? mean : EPS;
        fano = (float)(var / m);
    }
    for (int off = 32; off > 0; off >>= 1) fano += __shfl_down(fano, off);
    if (lane == 0) sf[wid] = fano / (float)C_CLS;
    __syncthreads();
    if (wid == 0) {
        float sq = 0.f;
        if (lane < NBINS) {
            float d = exp_fanos[lane] - sf[lane];
            sq = d * d;
        }
        for (int off = 32; off > 0; off >>= 1) sq += __shfl_down(sq, off);
        if (lane == 0) out[0] = 10.0f * sq / (float)NBINS;
    }
}

extern "C" void kernel_launch(void* const* d_in, const int* in_sizes, int n_in,
                              void* d_out, int out_size, void* d_ws, size_t ws_size,
                              hipStream_t stream) {
    const float* spikes    = (const float*)d_in[0];
    const float* exp_fanos = (const float*)d_in[1];
    const int*   trials    = (const int*)d_in[2];
    const void*  mask      = d_in[3];
    float* out = (float*)d_out;

    char* ws = (char*)d_ws;
    int*   verdict = (int*)(ws + 0);
    int*   ncls    = (int*)(ws + 1024);
    int*   clsofb  = (int*)(ws + 1280);
    unsigned long long* bits = (unsigned long long*)(ws + 8192);   // 204,800 B
    float* selected = (float*)(ws + 212992);                       // 100,000 B

    detect_kernel<<<256, 256, 0, stream>>>((const unsigned int*)mask, trials,
                                           verdict, ncls, clsofb);
    build_bits_kernel<<<dim3(C_CLS, 8), 64, 0, stream>>>(mask, verdict, bits);
    stream_kernel<<<NBT, 256, 0, stream>>>(spikes, ncls, clsofb, bits, selected);
    fano_loss_kernel<<<1, 1024, 0, stream>>>(selected, exp_fanos, out);
}